// Round 8
// baseline (1288.873 us; speedup 1.0000x reference)
//
#include <hip/hip_runtime.h>

// ---------------------------------------------------------------------------
// GCN: bucketed CSR-by-dst build + 5 x (MFMA GEMM / XCD-sliced gather) + pool
// + MLP. Activations/tables bf16 (incoherent rounding, averages out in the
// mean-pool); weights split hi+lo bf16 (2x MFMA) so coherent weight error
// stays ~4e-6. All accumulation fp32.
// Gather: column-sliced so each XCD's 16-col slice (3.2MB) stays L2-resident
// (blockIdx%NSL -> XCD round-robin); csr/rowptr via non-temporal loads so the
// stream doesn't evict the slice. r6 measured 189MB fetch = 8 XCDs x table.
// CSR build: histogram -> bucket-major staging -> LDS-cursor scatter (random
// 4B scatter to HBM costs 64B/edge; measured 100MB writes r2-r4).
// ---------------------------------------------------------------------------

static constexpr int TPB = 256;
static constexpr int NBKT = 128;   // dst buckets: bucket = dst >> 10
static constexpr int NCHK = 256;   // edge chunks

using f32x4  = __attribute__((ext_vector_type(4))) float;
using u32x4  = __attribute__((ext_vector_type(4))) unsigned;
using bf16x8 = __attribute__((ext_vector_type(8))) short;

__device__ __forceinline__ float u2f(unsigned u) { return __uint_as_float(u); }

// fp32 -> bf16 RNE
__device__ __forceinline__ unsigned short bf1(float a) {
    unsigned u = __float_as_uint(a);
    u += 0x7FFFu + ((u >> 16) & 1u);
    return (unsigned short)(u >> 16);
}

// pack two fp32 -> two bf16 (RNE) in one uint
__device__ __forceinline__ unsigned bf2(float a, float b) {
    unsigned ua = __float_as_uint(a);
    unsigned ub = __float_as_uint(b);
    ua += 0x7FFFu + ((ua >> 16) & 1u);
    ub += 0x7FFFu + ((ub >> 16) & 1u);
    return (ua >> 16) | (ub & 0xFFFF0000u);
}

// ------------------------------- CSR build ---------------------------------
__global__ __launch_bounds__(256) void k_hist(const int* __restrict__ dst,
                                              int* __restrict__ histT, int E, int CS) {
    __shared__ int h[NBKT];
    int c = blockIdx.x, t = threadIdx.x;
    if (t < NBKT) h[t] = 0;
    __syncthreads();
    int e0 = c * CS, e1 = min(e0 + CS, E);
    for (int e = e0 + t; e < e1; e += 256)
        atomicAdd(&h[dst[e] >> 10], 1);
    __syncthreads();
    if (t < NBKT) histT[t * NCHK + c] = h[t];
}

__global__ __launch_bounds__(256) void k_scanS(const int* __restrict__ histT,
                                               int* __restrict__ stg) {
    constexpr int TOT = NBKT * NCHK;
    constexpr int PER = TOT / 256;
    __shared__ int s[256];
    int t = threadIdx.x;
    int base = t * PER;
    int sum = 0;
    for (int i = 0; i < PER; ++i) sum += histT[base + i];
    s[t] = sum;
    __syncthreads();
    for (int off = 1; off < 256; off <<= 1) {
        int add = (t >= off) ? s[t - off] : 0;
        __syncthreads();
        s[t] += add;
        __syncthreads();
    }
    int run = (t > 0) ? s[t - 1] : 0;
    for (int i = 0; i < PER; ++i) {
        stg[base + i] = run;
        run += histT[base + i];
    }
}

__global__ __launch_bounds__(256) void k_bucket(const int* __restrict__ src,
                                                const int* __restrict__ dst,
                                                const int* __restrict__ stg,
                                                unsigned* __restrict__ staging,
                                                int E, int CS) {
    __shared__ int cur[NBKT];
    int c = blockIdx.x, t = threadIdx.x;
    if (t < NBKT) cur[t] = stg[t * NCHK + c];
    __syncthreads();
    int e0 = c * CS, e1 = min(e0 + CS, E);
    for (int e = e0 + t; e < e1; e += 256) {
        int d = dst[e];
        int p = atomicAdd(&cur[d >> 10], 1);
        staging[p] = ((unsigned)src[e] << 10) | (unsigned)(d & 1023);
    }
}

__global__ __launch_bounds__(256) void k_deg(const unsigned* __restrict__ staging,
                                             const int* __restrict__ stg,
                                             int* __restrict__ cnt, int E, int n) {
    __shared__ int deg[1024];
    int r = blockIdx.x, t = threadIdx.x;
    for (int i = t; i < 1024; i += 256) deg[i] = 0;
    __syncthreads();
    int s0 = stg[r * NCHK];
    int s1 = (r == NBKT - 1) ? E : stg[(r + 1) * NCHK];
    for (int e = s0 + t; e < s1; e += 256)
        atomicAdd(&deg[staging[e] & 1023u], 1);
    __syncthreads();
    int b = r << 10;
    for (int i = t; i < 1024; i += 256)
        if (b + i < n) cnt[b + i] = deg[i];
}

__global__ void k_scanA(const int* __restrict__ cnt, int* __restrict__ rowptr,
                        int* __restrict__ bsum, int n) {
    __shared__ int s[TPB];
    int t = threadIdx.x;
    int i = blockIdx.x * TPB + t;
    s[t] = (i < n) ? cnt[i] : 0;
    __syncthreads();
    for (int off = 1; off < TPB; off <<= 1) {
        int add = (t >= off) ? s[t - off] : 0;
        __syncthreads();
        s[t] += add;
        __syncthreads();
    }
    if (i < n) rowptr[i + 1] = s[t];
    if (t == TPB - 1) bsum[blockIdx.x] = s[t];
}

__global__ void k_scanB(const int* __restrict__ bsum, int* __restrict__ bscan, int nb) {
    __shared__ int s[512];
    int t = threadIdx.x;
    s[t] = (t < nb) ? bsum[t] : 0;
    __syncthreads();
    for (int off = 1; off < 512; off <<= 1) {
        int add = (t >= off) ? s[t - off] : 0;
        __syncthreads();
        s[t] += add;
        __syncthreads();
    }
    if (t < nb) bscan[t] = (t > 0) ? s[t - 1] : 0;
}

__global__ void k_scanC(int* __restrict__ rowptr, const int* __restrict__ bscan,
                        const int* __restrict__ cnt, float* __restrict__ dinv, int n) {
    int i = blockIdx.x * blockDim.x + threadIdx.x;
    if (i >= n) return;
    rowptr[i + 1] += bscan[i >> 8];
    dinv[i] = rsqrtf((float)cnt[i] + 1.0f);
    if (i == 0) rowptr[0] = 0;
}

__global__ __launch_bounds__(256) void k_fill2(const unsigned* __restrict__ staging,
                                               const int* __restrict__ stg,
                                               const int* __restrict__ rowptr,
                                               int* __restrict__ csr, int E, int n) {
    __shared__ int cur[1024];
    int r = blockIdx.x, t = threadIdx.x;
    int b = r << 10;
    for (int i = t; i < 1024; i += 256)
        cur[i] = (b + i < n) ? rowptr[b + i] : 0;
    __syncthreads();
    int s0 = stg[r * NCHK];
    int s1 = (r == NBKT - 1) ? E : stg[(r + 1) * NCHK];
    for (int e = s0 + t; e < s1; e += 256) {
        unsigned sd = staging[e];
        int p = atomicAdd(&cur[sd & 1023u], 1);
        csr[p] = (int)(sd >> 10);
    }
}

// xs[i,k] = bf16(x[i,k] * dinv[i]); 8 elems/thread
__global__ void k_castx(const float* __restrict__ x, const float* __restrict__ dinv,
                        unsigned short* __restrict__ xs, int n) {
    int gid = blockIdx.x * blockDim.x + threadIdx.x;
    if (gid >= n * 8) return;
    int row = gid >> 3;
    float d = dinv[row];
    const float4* xp = (const float4*)x + (size_t)gid * 2;
    float4 a = xp[0], b = xp[1];
    uint4 o;
    o.x = bf2(a.x * d, a.y * d);
    o.y = bf2(a.z * d, a.w * d);
    o.z = bf2(b.x * d, b.y * d);
    o.w = bf2(b.z * d, b.w * d);
    ((uint4*)xs)[gid] = o;
}

// ---------------------- weight prep: W -> W^T hi/lo bf16 -------------------
__global__ void k_prepw(const float* __restrict__ W1, const float* __restrict__ W2,
                        const float* __restrict__ W3, const float* __restrict__ W4,
                        const float* __restrict__ Wo,
                        unsigned short* __restrict__ wt1, unsigned short* __restrict__ wt2,
                        unsigned short* __restrict__ wt3, unsigned short* __restrict__ wt4,
                        unsigned short* __restrict__ wto) {
    int b = blockIdx.x, k = threadIdx.x;
    const float* W; unsigned short* wt; int K, OUT, nn;
    if (b < 128)      { W = W1; wt = wt1; K = 64;  OUT = 128; nn = b; }
    else if (b < 256) { W = W2; wt = wt2; K = 128; OUT = 128; nn = b - 128; }
    else if (b < 384) { W = W3; wt = wt3; K = 128; OUT = 128; nn = b - 256; }
    else if (b < 512) { W = W4; wt = wt4; K = 128; OUT = 128; nn = b - 384; }
    else              { W = Wo; wt = wto; K = 128; OUT = 32;  nn = b - 512; }
    if (nn >= OUT || k >= K) return;
    float v = W[(size_t)k * OUT + nn];
    unsigned short hi = bf1(v);
    float fhi = u2f((unsigned)hi << 16);
    unsigned short lo = bf1(v - fhi);
    wt[nn * K + k] = hi;
    wt[OUT * K + nn * K + k] = lo;
}

// ---------------------------- MFMA GEMM ------------------------------------
template <int K, int OUT, int EPI>
__global__ __launch_bounds__(256) void k_gemm_mfma(
    const unsigned short* __restrict__ Ain,
    const unsigned short* __restrict__ WT,
    const float* __restrict__ dinv,
    const float* __restrict__ bias,
    unsigned short* __restrict__ out, int n) {
    constexpr int NT = OUT / 16;   // n-tiles
    constexpr int KT = K / 32;     // k-tiles
    constexpr int CH = K / 8;      // 16B chunks per WT row
    __shared__ __align__(16) unsigned short Wl[2 * OUT * K];

    int t = threadIdx.x;
    {
        const uint4* wg = (const uint4*)WT;
        uint4* wl = (uint4*)Wl;
        for (int i = t; i < 2 * OUT * CH; i += 256) {
            int m = i / (OUT * CH);
            int r = i - m * (OUT * CH);
            int nn = r / CH, g = r - nn * CH;
            wl[m * OUT * CH + nn * CH + (g ^ (nn & 7))] = wg[i];
        }
    }

    int wid = t >> 6, lane = t & 63;
    int lr = lane & 15, lg = lane >> 4;
    int mbase = blockIdx.x * 128 + wid * 32;

    bf16x8 a[2][KT];
#pragma unroll
    for (int mt = 0; mt < 2; ++mt) {
        int row = mbase + mt * 16 + lr;
        row = row < n ? row : n - 1;
        const bf16x8* ap = (const bf16x8*)(Ain + (size_t)row * K);
#pragma unroll
        for (int kt = 0; kt < KT; ++kt)
            a[mt][kt] = ap[kt * 4 + lg];
    }

    __syncthreads();

    f32x4 acc[2][NT] = {};
#pragma unroll
    for (int nt = 0; nt < NT; ++nt) {
        int nn = nt * 16 + lr;
        int swz = nn & 7;
        int rowoff = nn * K;
#pragma unroll
        for (int kt = 0; kt < KT; ++kt) {
            int g = kt * 4 + lg;
            int off = rowoff + ((g ^ swz) * 8);
            bf16x8 bhi = *(const bf16x8*)&Wl[off];
            bf16x8 blo = *(const bf16x8*)&Wl[OUT * K + off];
#pragma unroll
            for (int mt = 0; mt < 2; ++mt) {
                acc[mt][nt] = __builtin_amdgcn_mfma_f32_16x16x32_bf16(
                    a[mt][kt], bhi, acc[mt][nt], 0, 0, 0);
                acc[mt][nt] = __builtin_amdgcn_mfma_f32_16x16x32_bf16(
                    a[mt][kt], blo, acc[mt][nt], 0, 0, 0);
            }
        }
    }

#pragma unroll
    for (int mt = 0; mt < 2; ++mt) {
        int rbase = mbase + mt * 16 + lg * 4;
        float dv[4];
        if (EPI == 0) {
#pragma unroll
            for (int r = 0; r < 4; ++r)
                dv[r] = (rbase + r < n) ? dinv[rbase + r] : 0.f;
        }
#pragma unroll
        for (int nt = 0; nt < NT; ++nt) {
            int col = nt * 16 + lr;
            float bb = (EPI == 1) ? bias[col] : 0.f;
#pragma unroll
            for (int r = 0; r < 4; ++r) {
                int row = rbase + r;
                if (row < n) {
                    float v = acc[mt][nt][r];
                    if (EPI == 0) v *= dv[r];
                    else v = fmaxf(v + bb, 0.f);
                    out[(size_t)row * OUT + col] = bf1(v);
                }
            }
        }
    }
}

// ----------------------- XCD-sliced gather (bf16 table) --------------------
__device__ __forceinline__ void addbf(float* acc, u32x4 w) {
    acc[0] += u2f(w.x << 16); acc[1] += u2f(w.x & 0xFFFF0000u);
    acc[2] += u2f(w.y << 16); acc[3] += u2f(w.y & 0xFFFF0000u);
    acc[4] += u2f(w.z << 16); acc[5] += u2f(w.z & 0xFFFF0000u);
    acc[6] += u2f(w.w << 16); acc[7] += u2f(w.w & 0xFFFF0000u);
}

// out_i = [relu]( dinv_i * (hs_i + sum_j hs_j) [+ bias] )
// Column-sliced: block handles 16 cols (slice = blockIdx % NSL); NSL | 8 so
// each XCD sees exactly one slice (3.2MB, L2-resident). 2 lanes/node.
// csr/rowptr non-temporal (don't evict slice); out stores non-temporal.
template <int D, bool RELU, bool HASBIAS, bool OUTBF>
__global__ __launch_bounds__(256) void k_gather_sl(
    const unsigned short* __restrict__ hsb,
    const int* __restrict__ rowptr, const int* __restrict__ csr,
    const float* __restrict__ dinv, const float* __restrict__ bias,
    void* __restrict__ outp, int n) {
    constexpr int NSL = D / 16;    // slices (8 / 4 / 2)
    constexpr int RW = D / 8;      // u32x4 per table row
    int slice = blockIdx.x % NSL;
    int nb = blockIdx.x / NSL;
    int t = threadIdx.x;
    int node = nb * 128 + (t >> 1);
    if (node >= n) return;
    int cidx = slice * 2 + (t & 1);   // u32x4 index within row
    const u32x4* hb = (const u32x4*)hsb;

    float acc[8];
    {
        u32x4 v = hb[(size_t)node * RW + cidx];
        acc[0] = u2f(v.x << 16); acc[1] = u2f(v.x & 0xFFFF0000u);
        acc[2] = u2f(v.y << 16); acc[3] = u2f(v.y & 0xFFFF0000u);
        acc[4] = u2f(v.z << 16); acc[5] = u2f(v.z & 0xFFFF0000u);
        acc[6] = u2f(v.w << 16); acc[7] = u2f(v.w & 0xFFFF0000u);
    }
    int j0 = __builtin_nontemporal_load(&rowptr[node]);
    int j1 = __builtin_nontemporal_load(&rowptr[node + 1]);
    int j = j0;
    for (; j + 3 < j1; j += 4) {
        int s0 = __builtin_nontemporal_load(&csr[j]);
        int s1 = __builtin_nontemporal_load(&csr[j + 1]);
        int s2 = __builtin_nontemporal_load(&csr[j + 2]);
        int s3 = __builtin_nontemporal_load(&csr[j + 3]);
        u32x4 w0 = hb[(size_t)s0 * RW + cidx];
        u32x4 w1 = hb[(size_t)s1 * RW + cidx];
        u32x4 w2 = hb[(size_t)s2 * RW + cidx];
        u32x4 w3 = hb[(size_t)s3 * RW + cidx];
        addbf(acc, w0); addbf(acc, w1); addbf(acc, w2); addbf(acc, w3);
    }
    for (; j < j1; ++j) {
        int s0 = __builtin_nontemporal_load(&csr[j]);
        u32x4 w0 = hb[(size_t)s0 * RW + cidx];
        addbf(acc, w0);
    }

    float di = dinv[node];
    float r[8];
    if (HASBIAS) {
        float4 b0 = *(const float4*)&bias[cidx * 8];
        float4 b1 = *(const float4*)&bias[cidx * 8 + 4];
        r[0] = di * acc[0] + b0.x; r[1] = di * acc[1] + b0.y;
        r[2] = di * acc[2] + b0.z; r[3] = di * acc[3] + b0.w;
        r[4] = di * acc[4] + b1.x; r[5] = di * acc[5] + b1.y;
        r[6] = di * acc[6] + b1.z; r[7] = di * acc[7] + b1.w;
    } else {
#pragma unroll
        for (int i = 0; i < 8; ++i) r[i] = di * acc[i];
    }
    if (RELU) {
#pragma unroll
        for (int i = 0; i < 8; ++i) r[i] = fmaxf(r[i], 0.f);
    }
    if (OUTBF) {
        u32x4 o;
        o.x = bf2(r[0], r[1]); o.y = bf2(r[2], r[3]);
        o.z = bf2(r[4], r[5]); o.w = bf2(r[6], r[7]);
        __builtin_nontemporal_store(o, &((u32x4*)outp)[(size_t)node * RW + cidx]);
    } else {
        f32x4 o0 = {r[0], r[1], r[2], r[3]};
        f32x4 o1 = {r[4], r[5], r[6], r[7]};
        f32x4* op = (f32x4*)outp + (size_t)node * (D / 4) + cidx * 2;
        __builtin_nontemporal_store(o0, op);
        __builtin_nontemporal_store(o1, op + 1);
    }
}

// ------------------------------ pool + MLP ---------------------------------
__global__ __launch_bounds__(256) void k_pool(const float* __restrict__ h,
                                              const int* __restrict__ batch,
                                              float* __restrict__ g, int n) {
    __shared__ int se[2];
    __shared__ float red[8][32];
    int gi = blockIdx.x;
    int t = threadIdx.x;
    if (t == 0) {
        int lo = 0, hi = n;
        while (lo < hi) { int m = (lo + hi) >> 1; if (batch[m] < gi) lo = m + 1; else hi = m; }
        se[0] = lo;
        lo = 0; hi = n;
        while (lo < hi) { int m = (lo + hi) >> 1; if (batch[m] < gi + 1) lo = m + 1; else hi = m; }
        se[1] = lo;
    }
    __syncthreads();
    int start = se[0], end = se[1];
    int col = t & 31, sub = t >> 5;
    float acc = 0.f;
    for (int i = start + sub; i < end; i += 8)
        acc += h[(size_t)i * 32 + col];
    red[sub][col] = acc;
    __syncthreads();
    if (t < 32) {
        float s = 0.f;
#pragma unroll
        for (int q = 0; q < 8; ++q) s += red[q][t];
        float c = (float)(end - start);
        g[gi * 32 + t] = s / fmaxf(c, 1.0f);
    }
}

template <int K, int O, bool RELU>
__global__ void k_mlp(const float* __restrict__ in, const float* __restrict__ W,
                      const float* __restrict__ b, float* __restrict__ out, int G) {
    int gid = blockIdx.x * blockDim.x + threadIdx.x;
    if (gid >= G * O) return;
    int g = gid / O, j = gid % O;
    float s = b[j];
    for (int k = 0; k < K; ++k) s += in[g * K + k] * W[k * O + j];
    if (RELU) s = fmaxf(s, 0.f);
    out[gid] = s;
}

// ------------------------------- launch ------------------------------------
extern "C" void kernel_launch(void* const* d_in, const int* in_sizes, int n_in,
                              void* d_out, int out_size, void* d_ws, size_t ws_size,
                              hipStream_t stream) {
    const float* x    = (const float*)d_in[0];
    const int*   ei   = (const int*)d_in[1];
    const int*   batch= (const int*)d_in[2];
    const float* W1 = (const float*)d_in[3];  const float* b1 = (const float*)d_in[4];
    const float* W2 = (const float*)d_in[5];  const float* b2 = (const float*)d_in[6];
    const float* W3 = (const float*)d_in[7];  const float* b3 = (const float*)d_in[8];
    const float* W4 = (const float*)d_in[9];  const float* b4 = (const float*)d_in[10];
    const float* Wo = (const float*)d_in[11]; const float* bo = (const float*)d_in[12];
    const float* M1w = (const float*)d_in[13]; const float* M1b = (const float*)d_in[14];
    const float* M2w = (const float*)d_in[15]; const float* M2b = (const float*)d_in[16];
    const float* M3w = (const float*)d_in[17]; const float* M3b = (const float*)d_in[18];

    const int N = in_sizes[0] / 64;   // 100000
    const int E = in_sizes[1] / 2;    // 1600000
    const int G = out_size / 8;       // 64
    const int* src  = ei;
    const int* dstp = ei + E;

    // workspace
    char* w = (char*)d_ws;
    unsigned short* buf1 = (unsigned short*)w; w += (size_t)N * 128 * 2;
    unsigned short* buf2 = (unsigned short*)w; w += (size_t)N * 128 * 2;
    unsigned short* hsb  = (unsigned short*)w; w += (size_t)N * 128 * 2;
    int*      csr     = (int*)w;      w += (size_t)E * 4;
    unsigned* staging = (unsigned*)w; w += (size_t)E * 4;
    int*      histT   = (int*)w;      w += NBKT * NCHK * 4;
    int*      stg     = (int*)w;      w += NBKT * NCHK * 4;
    int*      cnt     = (int*)w;      w += (size_t)N * 4;
    int*      rowptr  = (int*)w;      w += (size_t)(N + 4) * 4;
    int*      bsum    = (int*)w;      w += 4096;
    int*      bscan   = (int*)w;      w += 4096;
    float*    dinv    = (float*)w;    w += (size_t)N * 4;
    unsigned short* wt1 = (unsigned short*)w; w += 2 * 128 * 64 * 2;
    unsigned short* wt2 = (unsigned short*)w; w += 2 * 128 * 128 * 2;
    unsigned short* wt3 = (unsigned short*)w; w += 2 * 128 * 128 * 2;
    unsigned short* wt4 = (unsigned short*)w; w += 2 * 128 * 128 * 2;
    unsigned short* wto = (unsigned short*)w; w += 2 * 32 * 128 * 2;
    float*    gp      = (float*)w;    w += 64 * 32 * 4;
    float*    m1      = (float*)w;    w += 64 * 64 * 4;
    float*    m2      = (float*)w;    w += 64 * 16 * 4;

    const int NB = (N + TPB - 1) / TPB;
    const int CS = (E + NCHK - 1) / NCHK;
    const int GB = (N + 127) / 128;       // MFMA GEMM grid (BM=128)
    const int SB = (N + 127) / 128;       // node-blocks per slice (128 nodes)

    // ---- CSR build + weight prep ----
    k_hist<<<NCHK, 256, 0, stream>>>(dstp, histT, E, CS);
    k_prepw<<<544, 128, 0, stream>>>(W1, W2, W3, W4, Wo, wt1, wt2, wt3, wt4, wto);
    k_scanS<<<1, 256, 0, stream>>>(histT, stg);
    k_bucket<<<NCHK, 256, 0, stream>>>(src, dstp, stg, staging, E, CS);
    k_deg<<<NBKT, 256, 0, stream>>>(staging, stg, cnt, E, N);
    k_scanA<<<NB, TPB, 0, stream>>>(cnt, rowptr, bsum, N);
    k_scanB<<<1, 512, 0, stream>>>(bsum, bscan, NB);
    k_scanC<<<NB, TPB, 0, stream>>>(rowptr, bscan, cnt, dinv, N);
    k_fill2<<<NBKT, 256, 0, stream>>>(staging, stg, rowptr, csr, E, N);

    unsigned short* agg = buf1;
    unsigned short* xs  = buf2;

    // Layer 1 (aggregate-first on 64-dim)
    k_castx<<<(N * 8 + 255) / 256, 256, 0, stream>>>(x, dinv, xs, N);
    k_gather_sl<64, false, false, true><<<4 * SB, 256, 0, stream>>>(
        xs, rowptr, csr, dinv, nullptr, agg, N);
    k_gemm_mfma<64, 128, 1><<<GB, 256, 0, stream>>>(agg, wt1, nullptr, b1, buf2, N);

    // Layers 2-4
    k_gemm_mfma<128, 128, 0><<<GB, 256, 0, stream>>>(buf2, wt2, dinv, nullptr, hsb, N);
    k_gather_sl<128, true, true, true><<<8 * SB, 256, 0, stream>>>(
        hsb, rowptr, csr, dinv, b2, buf1, N);
    k_gemm_mfma<128, 128, 0><<<GB, 256, 0, stream>>>(buf1, wt3, dinv, nullptr, hsb, N);
    k_gather_sl<128, true, true, true><<<8 * SB, 256, 0, stream>>>(
        hsb, rowptr, csr, dinv, b3, buf2, N);
    k_gemm_mfma<128, 128, 0><<<GB, 256, 0, stream>>>(buf2, wt4, dinv, nullptr, hsb, N);
    k_gather_sl<128, true, true, true><<<8 * SB, 256, 0, stream>>>(
        hsb, rowptr, csr, dinv, b4, buf1, N);

    // Layer 5: 128 -> 32 (fp32 out for pool)
    k_gemm_mfma<128, 32, 0><<<GB, 256, 0, stream>>>(buf1, wto, dinv, nullptr, hsb, N);
    float* hout = (float*)buf2;
    k_gather_sl<32, false, true, false><<<2 * SB, 256, 0, stream>>>(
        hsb, rowptr, csr, dinv, bo, hout, N);

    // Mean pool + MLP head
    k_pool<<<G, 256, 0, stream>>>(hout, batch, gp, N);
    k_mlp<32, 64, true><<<(G * 64 + 255) / 256, 256, 0, stream>>>(gp, M1w, M1b, m1, G);
    k_mlp<64, 16, true><<<(G * 16 + 255) / 256, 256, 0, stream>>>(m1, M2w, M2b, m2, G);
    k_mlp<16, 8, false><<<(G * 8 + 255) / 256, 256, 0, stream>>>(m2, M3w, M3b, (float*)d_out, G);
}

// Round 9
// 837.054 us; speedup vs baseline: 1.5398x; 1.5398x over previous
//
#include <hip/hip_runtime.h>

// ---------------------------------------------------------------------------
// GCN: bucketed CSR-by-dst build + 5 x (MFMA GEMM / XCD-pinned sliced gather)
// + pool + MLP. Activations/tables bf16 slice-major [slice][node][16cols]
// (3.2MB/slice fits a 4MB XCD L2); gather blocks claim their own XCD's slice
// via s_getreg(HW_REG_XCC_ID) + per-slice atomic work queue (steal on full).
// r8 lesson: row-major 16-col slices waste half of every 64B line and the
// blockIdx%8->XCD guess gave zero residency (FETCH 787MB = 2x issued).
// Weights split hi+lo bf16 (2x MFMA, coherent error ~4e-6); accum fp32.
// ---------------------------------------------------------------------------

static constexpr int TPB = 256;
static constexpr int NBKT = 128;   // dst buckets: bucket = dst >> 10
static constexpr int NCHK = 256;   // edge chunks

using f32x4  = __attribute__((ext_vector_type(4))) float;
using u32x4  = __attribute__((ext_vector_type(4))) unsigned;
using bf16x8 = __attribute__((ext_vector_type(8))) short;

__device__ __forceinline__ float u2f(unsigned u) { return __uint_as_float(u); }

__device__ __forceinline__ unsigned short bf1(float a) {
    unsigned u = __float_as_uint(a);
    u += 0x7FFFu + ((u >> 16) & 1u);
    return (unsigned short)(u >> 16);
}

__device__ __forceinline__ unsigned bf2(float a, float b) {
    unsigned ua = __float_as_uint(a);
    unsigned ub = __float_as_uint(b);
    ua += 0x7FFFu + ((ua >> 16) & 1u);
    ub += 0x7FFFu + ((ub >> 16) & 1u);
    return (ua >> 16) | (ub & 0xFFFF0000u);
}

// ------------------------------- CSR build ---------------------------------
__global__ __launch_bounds__(256) void k_hist(const int* __restrict__ dst,
                                              int* __restrict__ histT, int E, int CS) {
    __shared__ int h[NBKT];
    int c = blockIdx.x, t = threadIdx.x;
    if (t < NBKT) h[t] = 0;
    __syncthreads();
    int e0 = c * CS, e1 = min(e0 + CS, E);
    for (int e = e0 + t; e < e1; e += 256)
        atomicAdd(&h[dst[e] >> 10], 1);
    __syncthreads();
    if (t < NBKT) histT[t * NCHK + c] = h[t];
}

__global__ __launch_bounds__(256) void k_scanS(const int* __restrict__ histT,
                                               int* __restrict__ stg) {
    constexpr int TOT = NBKT * NCHK;
    constexpr int PER = TOT / 256;
    __shared__ int s[256];
    int t = threadIdx.x;
    int base = t * PER;
    int sum = 0;
    for (int i = 0; i < PER; ++i) sum += histT[base + i];
    s[t] = sum;
    __syncthreads();
    for (int off = 1; off < 256; off <<= 1) {
        int add = (t >= off) ? s[t - off] : 0;
        __syncthreads();
        s[t] += add;
        __syncthreads();
    }
    int run = (t > 0) ? s[t - 1] : 0;
    for (int i = 0; i < PER; ++i) {
        stg[base + i] = run;
        run += histT[base + i];
    }
}

__global__ __launch_bounds__(256) void k_bucket(const int* __restrict__ src,
                                                const int* __restrict__ dst,
                                                const int* __restrict__ stg,
                                                unsigned* __restrict__ staging,
                                                int E, int CS) {
    __shared__ int cur[NBKT];
    int c = blockIdx.x, t = threadIdx.x;
    if (t < NBKT) cur[t] = stg[t * NCHK + c];
    __syncthreads();
    int e0 = c * CS, e1 = min(e0 + CS, E);
    for (int e = e0 + t; e < e1; e += 256) {
        int d = dst[e];
        int p = atomicAdd(&cur[d >> 10], 1);
        staging[p] = ((unsigned)src[e] << 10) | (unsigned)(d & 1023);
    }
}

__global__ __launch_bounds__(256) void k_deg(const unsigned* __restrict__ staging,
                                             const int* __restrict__ stg,
                                             int* __restrict__ cnt, int E, int n) {
    __shared__ int deg[1024];
    int r = blockIdx.x, t = threadIdx.x;
    for (int i = t; i < 1024; i += 256) deg[i] = 0;
    __syncthreads();
    int s0 = stg[r * NCHK];
    int s1 = (r == NBKT - 1) ? E : stg[(r + 1) * NCHK];
    for (int e = s0 + t; e < s1; e += 256)
        atomicAdd(&deg[staging[e] & 1023u], 1);
    __syncthreads();
    int b = r << 10;
    for (int i = t; i < 1024; i += 256)
        if (b + i < n) cnt[b + i] = deg[i];
}

__global__ void k_scanA(const int* __restrict__ cnt, int* __restrict__ rowptr,
                        int* __restrict__ bsum, int n) {
    __shared__ int s[TPB];
    int t = threadIdx.x;
    int i = blockIdx.x * TPB + t;
    s[t] = (i < n) ? cnt[i] : 0;
    __syncthreads();
    for (int off = 1; off < TPB; off <<= 1) {
        int add = (t >= off) ? s[t - off] : 0;
        __syncthreads();
        s[t] += add;
        __syncthreads();
    }
    if (i < n) rowptr[i + 1] = s[t];
    if (t == TPB - 1) bsum[blockIdx.x] = s[t];
}

__global__ void k_scanB(const int* __restrict__ bsum, int* __restrict__ bscan, int nb) {
    __shared__ int s[512];
    int t = threadIdx.x;
    s[t] = (t < nb) ? bsum[t] : 0;
    __syncthreads();
    for (int off = 1; off < 512; off <<= 1) {
        int add = (t >= off) ? s[t - off] : 0;
        __syncthreads();
        s[t] += add;
        __syncthreads();
    }
    if (t < nb) bscan[t] = (t > 0) ? s[t - 1] : 0;
}

__global__ void k_scanC(int* __restrict__ rowptr, const int* __restrict__ bscan,
                        const int* __restrict__ cnt, float* __restrict__ dinv, int n) {
    int i = blockIdx.x * blockDim.x + threadIdx.x;
    if (i >= n) return;
    rowptr[i + 1] += bscan[i >> 8];
    dinv[i] = rsqrtf((float)cnt[i] + 1.0f);
    if (i == 0) rowptr[0] = 0;
}

__global__ __launch_bounds__(256) void k_fill2(const unsigned* __restrict__ staging,
                                               const int* __restrict__ stg,
                                               const int* __restrict__ rowptr,
                                               int* __restrict__ csr, int E, int n) {
    __shared__ int cur[1024];
    int r = blockIdx.x, t = threadIdx.x;
    int b = r << 10;
    for (int i = t; i < 1024; i += 256)
        cur[i] = (b + i < n) ? rowptr[b + i] : 0;
    __syncthreads();
    int s0 = stg[r * NCHK];
    int s1 = (r == NBKT - 1) ? E : stg[(r + 1) * NCHK];
    for (int e = s0 + t; e < s1; e += 256) {
        unsigned sd = staging[e];
        int p = atomicAdd(&cur[sd & 1023u], 1);
        csr[p] = (int)(sd >> 10);
    }
}

// xs sliced: [slice][node][16 cols] bf16; xs4[(g>>1)*(n*2) + row*2 + (g&1)]
__global__ void k_castx(const float* __restrict__ x, const float* __restrict__ dinv,
                        unsigned short* __restrict__ xs, int n) {
    int gid = blockIdx.x * blockDim.x + threadIdx.x;
    if (gid >= n * 8) return;
    int row = gid >> 3;
    int g = gid & 7;          // 8-col group
    float d = dinv[row];
    const float4* xp = (const float4*)x + ((size_t)row * 8 + g) * 2;
    float4 a = xp[0], b = xp[1];
    uint4 o;
    o.x = bf2(a.x * d, a.y * d);
    o.y = bf2(a.z * d, a.w * d);
    o.z = bf2(b.x * d, b.y * d);
    o.w = bf2(b.z * d, b.w * d);
    ((uint4*)xs)[(size_t)(g >> 1) * ((size_t)n * 2) + (size_t)row * 2 + (g & 1)] = o;
}

// ---------------------- weight prep: W -> W^T hi/lo bf16 -------------------
__global__ void k_prepw(const float* __restrict__ W1, const float* __restrict__ W2,
                        const float* __restrict__ W3, const float* __restrict__ W4,
                        const float* __restrict__ Wo,
                        unsigned short* __restrict__ wt1, unsigned short* __restrict__ wt2,
                        unsigned short* __restrict__ wt3, unsigned short* __restrict__ wt4,
                        unsigned short* __restrict__ wto) {
    int b = blockIdx.x, k = threadIdx.x;
    const float* W; unsigned short* wt; int K, OUT, nn;
    if (b < 128)      { W = W1; wt = wt1; K = 64;  OUT = 128; nn = b; }
    else if (b < 256) { W = W2; wt = wt2; K = 128; OUT = 128; nn = b - 128; }
    else if (b < 384) { W = W3; wt = wt3; K = 128; OUT = 128; nn = b - 256; }
    else if (b < 512) { W = W4; wt = wt4; K = 128; OUT = 128; nn = b - 384; }
    else              { W = Wo; wt = wto; K = 128; OUT = 32;  nn = b - 512; }
    if (nn >= OUT || k >= K) return;
    float v = W[(size_t)k * OUT + nn];
    unsigned short hi = bf1(v);
    float fhi = u2f((unsigned)hi << 16);
    unsigned short lo = bf1(v - fhi);
    wt[nn * K + k] = hi;
    wt[OUT * K + nn * K + k] = lo;
}

// ---------------------------- MFMA GEMM ------------------------------------
// A and out both slice-major: elem (row,col) at (col>>4)*n*16 + row*16 + (col&15)
template <int K, int OUT, int EPI>
__global__ __launch_bounds__(256) void k_gemm_mfma(
    const unsigned short* __restrict__ Ain,
    const unsigned short* __restrict__ WT,
    const float* __restrict__ dinv,
    const float* __restrict__ bias,
    unsigned short* __restrict__ out, int n) {
    constexpr int NT = OUT / 16;   // n-tiles
    constexpr int KT = K / 32;     // k-tiles
    constexpr int CH = K / 8;      // 16B chunks per WT row
    __shared__ __align__(16) unsigned short Wl[2 * OUT * K];

    int t = threadIdx.x;
    {
        const uint4* wg = (const uint4*)WT;
        uint4* wl = (uint4*)Wl;
        for (int i = t; i < 2 * OUT * CH; i += 256) {
            int m = i / (OUT * CH);
            int r = i - m * (OUT * CH);
            int nn = r / CH, g = r - nn * CH;
            wl[m * OUT * CH + nn * CH + (g ^ (nn & 7))] = wg[i];
        }
    }

    int wid = t >> 6, lane = t & 63;
    int lr = lane & 15, lg = lane >> 4;
    int mbase = blockIdx.x * 128 + wid * 32;
    size_t n16 = (size_t)n * 16;

    bf16x8 a[2][KT];
#pragma unroll
    for (int mt = 0; mt < 2; ++mt) {
        int row = mbase + mt * 16 + lr;
        row = row < n ? row : n - 1;
#pragma unroll
        for (int kt = 0; kt < KT; ++kt) {
            int c8 = kt * 4 + lg;   // 8-col chunk index
            a[mt][kt] = *(const bf16x8*)(Ain + (size_t)(c8 >> 1) * n16 +
                                         (size_t)row * 16 + (c8 & 1) * 8);
        }
    }

    __syncthreads();

    f32x4 acc[2][NT] = {};
#pragma unroll
    for (int nt = 0; nt < NT; ++nt) {
        int nn = nt * 16 + lr;
        int swz = nn & 7;
        int rowoff = nn * K;
#pragma unroll
        for (int kt = 0; kt < KT; ++kt) {
            int g = kt * 4 + lg;
            int off = rowoff + ((g ^ swz) * 8);
            bf16x8 bhi = *(const bf16x8*)&Wl[off];
            bf16x8 blo = *(const bf16x8*)&Wl[OUT * K + off];
#pragma unroll
            for (int mt = 0; mt < 2; ++mt) {
                acc[mt][nt] = __builtin_amdgcn_mfma_f32_16x16x32_bf16(
                    a[mt][kt], bhi, acc[mt][nt], 0, 0, 0);
                acc[mt][nt] = __builtin_amdgcn_mfma_f32_16x16x32_bf16(
                    a[mt][kt], blo, acc[mt][nt], 0, 0, 0);
            }
        }
    }

#pragma unroll
    for (int mt = 0; mt < 2; ++mt) {
        int rbase = mbase + mt * 16 + lg * 4;
        float dv[4];
        if (EPI == 0) {
#pragma unroll
            for (int r = 0; r < 4; ++r)
                dv[r] = (rbase + r < n) ? dinv[rbase + r] : 0.f;
        }
#pragma unroll
        for (int nt = 0; nt < NT; ++nt) {
            int col = nt * 16 + lr;
            float bb = (EPI == 1) ? bias[col] : 0.f;
            size_t sb = (size_t)(col >> 4) * n16 + (col & 15);
#pragma unroll
            for (int r = 0; r < 4; ++r) {
                int row = rbase + r;
                if (row < n) {
                    float v = acc[mt][nt][r];
                    if (EPI == 0) v *= dv[r];
                    else v = fmaxf(v + bb, 0.f);
                    out[sb + (size_t)row * 16] = bf1(v);
                }
            }
        }
    }
}

// ------------------- XCD-pinned sliced gather (bf16 table) -----------------
__device__ __forceinline__ void addbf(float* acc, u32x4 w) {
    acc[0] += u2f(w.x << 16); acc[1] += u2f(w.x & 0xFFFF0000u);
    acc[2] += u2f(w.y << 16); acc[3] += u2f(w.y & 0xFFFF0000u);
    acc[4] += u2f(w.z << 16); acc[5] += u2f(w.z & 0xFFFF0000u);
    acc[6] += u2f(w.w << 16); acc[7] += u2f(w.w & 0xFFFF0000u);
}

// out_i = [relu]( dinv_i * (hs_i + sum_j hs_j) [+ bias] )
// Table slice-major [NSL][n][16cols]; block claims slice == its own XCD
// (s_getreg HW_REG_XCC_ID, m09-verified) via per-slice work queue; steals
// from neighbors when full (every work item claimed exactly once).
template <int D, bool RELU, bool HASBIAS, bool OUTBF>
__global__ __launch_bounds__(256) void k_gather_x(
    const unsigned short* __restrict__ hsb,
    const int* __restrict__ rowptr, const int* __restrict__ csr,
    const float* __restrict__ dinv, const float* __restrict__ bias,
    void* __restrict__ outp, int* __restrict__ qctr, int n, int SB) {
    constexpr int NSL = D / 16;    // 8 / 4 / 2 slices
    __shared__ int sw[2];
    if (threadIdx.x == 0) {
        unsigned xcc;
        asm volatile("s_getreg_b32 %0, hwreg(HW_REG_XCC_ID)" : "=s"(xcc));
        int slice = -1, nb = 0;
        for (int k = 0; k < NSL; ++k) {
            int s = (int)((xcc + (unsigned)k) & (NSL - 1));
            int idx = atomicAdd(&qctr[s], 1);
            if (idx < SB) { slice = s; nb = idx; break; }
        }
        sw[0] = slice; sw[1] = nb;
    }
    __syncthreads();
    int slice = sw[0];
    if (slice < 0) return;
    int t = threadIdx.x;
    int node = sw[1] * 128 + (t >> 1);
    if (node >= n) return;
    int half = t & 1;
    const u32x4* hb = (const u32x4*)hsb + (size_t)slice * n * 2;

    float acc[8];
    {
        u32x4 v = hb[(size_t)node * 2 + half];
        acc[0] = u2f(v.x << 16); acc[1] = u2f(v.x & 0xFFFF0000u);
        acc[2] = u2f(v.y << 16); acc[3] = u2f(v.y & 0xFFFF0000u);
        acc[4] = u2f(v.z << 16); acc[5] = u2f(v.z & 0xFFFF0000u);
        acc[6] = u2f(v.w << 16); acc[7] = u2f(v.w & 0xFFFF0000u);
    }
    int j0 = rowptr[node], j1 = rowptr[node + 1];
    int j = j0;
    for (; j + 3 < j1; j += 4) {
        int s0 = csr[j], s1 = csr[j + 1], s2 = csr[j + 2], s3 = csr[j + 3];
        u32x4 w0 = hb[(size_t)s0 * 2 + half];
        u32x4 w1 = hb[(size_t)s1 * 2 + half];
        u32x4 w2 = hb[(size_t)s2 * 2 + half];
        u32x4 w3 = hb[(size_t)s3 * 2 + half];
        addbf(acc, w0); addbf(acc, w1); addbf(acc, w2); addbf(acc, w3);
    }
    for (; j < j1; ++j) {
        u32x4 w0 = hb[(size_t)csr[j] * 2 + half];
        addbf(acc, w0);
    }

    float di = dinv[node];
    float r[8];
    if (HASBIAS) {
        int cb = slice * 16 + half * 8;
        float4 b0 = *(const float4*)&bias[cb];
        float4 b1 = *(const float4*)&bias[cb + 4];
        r[0] = di * acc[0] + b0.x; r[1] = di * acc[1] + b0.y;
        r[2] = di * acc[2] + b0.z; r[3] = di * acc[3] + b0.w;
        r[4] = di * acc[4] + b1.x; r[5] = di * acc[5] + b1.y;
        r[6] = di * acc[6] + b1.z; r[7] = di * acc[7] + b1.w;
    } else {
#pragma unroll
        for (int i = 0; i < 8; ++i) r[i] = di * acc[i];
    }
    if (RELU) {
#pragma unroll
        for (int i = 0; i < 8; ++i) r[i] = fmaxf(r[i], 0.f);
    }
    if (OUTBF) {
        u32x4 o;
        o.x = bf2(r[0], r[1]); o.y = bf2(r[2], r[3]);
        o.z = bf2(r[4], r[5]); o.w = bf2(r[6], r[7]);
        ((u32x4*)outp)[(size_t)slice * n * 2 + (size_t)node * 2 + half] = o;
    } else {
        f32x4 o0 = {r[0], r[1], r[2], r[3]};
        f32x4 o1 = {r[4], r[5], r[6], r[7]};
        f32x4* op = (f32x4*)outp +
                    ((size_t)slice * n * 16 + (size_t)node * 16 + half * 8) / 4;
        op[0] = o0;
        op[1] = o1;
    }
}

// ------------------------------ pool + MLP ---------------------------------
// h slice-major fp32: (col>>4)*n*16 + i*16 + (col&15)
__global__ __launch_bounds__(256) void k_pool(const float* __restrict__ h,
                                              const int* __restrict__ batch,
                                              float* __restrict__ g, int n) {
    __shared__ int se[2];
    __shared__ float red[8][32];
    int gi = blockIdx.x;
    int t = threadIdx.x;
    if (t == 0) {
        int lo = 0, hi = n;
        while (lo < hi) { int m = (lo + hi) >> 1; if (batch[m] < gi) lo = m + 1; else hi = m; }
        se[0] = lo;
        lo = 0; hi = n;
        while (lo < hi) { int m = (lo + hi) >> 1; if (batch[m] < gi + 1) lo = m + 1; else hi = m; }
        se[1] = lo;
    }
    __syncthreads();
    int start = se[0], end = se[1];
    int col = t & 31, sub = t >> 5;
    size_t sb = (size_t)(col >> 4) * ((size_t)n * 16) + (col & 15);
    float acc = 0.f;
    for (int i = start + sub; i < end; i += 8)
        acc += h[sb + (size_t)i * 16];
    red[sub][col] = acc;
    __syncthreads();
    if (t < 32) {
        float s = 0.f;
#pragma unroll
        for (int q = 0; q < 8; ++q) s += red[q][t];
        float c = (float)(end - start);
        g[gi * 32 + t] = s / fmaxf(c, 1.0f);
    }
}

template <int K, int O, bool RELU>
__global__ void k_mlp(const float* __restrict__ in, const float* __restrict__ W,
                      const float* __restrict__ b, float* __restrict__ out, int G) {
    int gid = blockIdx.x * blockDim.x + threadIdx.x;
    if (gid >= G * O) return;
    int g = gid / O, j = gid % O;
    float s = b[j];
    for (int k = 0; k < K; ++k) s += in[g * K + k] * W[k * O + j];
    if (RELU) s = fmaxf(s, 0.f);
    out[gid] = s;
}

// ------------------------------- launch ------------------------------------
extern "C" void kernel_launch(void* const* d_in, const int* in_sizes, int n_in,
                              void* d_out, int out_size, void* d_ws, size_t ws_size,
                              hipStream_t stream) {
    const float* x    = (const float*)d_in[0];
    const int*   ei   = (const int*)d_in[1];
    const int*   batch= (const int*)d_in[2];
    const float* W1 = (const float*)d_in[3];  const float* b1 = (const float*)d_in[4];
    const float* W2 = (const float*)d_in[5];  const float* b2 = (const float*)d_in[6];
    const float* W3 = (const float*)d_in[7];  const float* b3 = (const float*)d_in[8];
    const float* W4 = (const float*)d_in[9];  const float* b4 = (const float*)d_in[10];
    const float* Wo = (const float*)d_in[11]; const float* bo = (const float*)d_in[12];
    const float* M1w = (const float*)d_in[13]; const float* M1b = (const float*)d_in[14];
    const float* M2w = (const float*)d_in[15]; const float* M2b = (const float*)d_in[16];
    const float* M3w = (const float*)d_in[17]; const float* M3b = (const float*)d_in[18];

    const int N = in_sizes[0] / 64;   // 100000
    const int E = in_sizes[1] / 2;    // 1600000
    const int G = out_size / 8;       // 64
    const int* src  = ei;
    const int* dstp = ei + E;

    // workspace
    char* w = (char*)d_ws;
    unsigned short* buf1 = (unsigned short*)w; w += (size_t)N * 128 * 2;
    unsigned short* buf2 = (unsigned short*)w; w += (size_t)N * 128 * 4;  // also fp32 hout
    unsigned short* hsb  = (unsigned short*)w; w += (size_t)N * 128 * 2;
    int*      csr     = (int*)w;      w += (size_t)E * 4;
    unsigned* staging = (unsigned*)w; w += (size_t)E * 4;
    int*      histT   = (int*)w;      w += NBKT * NCHK * 4;
    int*      stg     = (int*)w;      w += NBKT * NCHK * 4;
    int*      cnt     = (int*)w;      w += (size_t)N * 4;
    int*      rowptr  = (int*)w;      w += (size_t)(N + 4) * 4;
    int*      bsum    = (int*)w;      w += 4096;
    int*      bscan   = (int*)w;      w += 4096;
    float*    dinv    = (float*)w;    w += (size_t)N * 4;
    int*      qctr    = (int*)w;      w += 6 * 8 * 4;   // 6 gathers x 8 slices
    unsigned short* wt1 = (unsigned short*)w; w += 2 * 128 * 64 * 2;
    unsigned short* wt2 = (unsigned short*)w; w += 2 * 128 * 128 * 2;
    unsigned short* wt3 = (unsigned short*)w; w += 2 * 128 * 128 * 2;
    unsigned short* wt4 = (unsigned short*)w; w += 2 * 128 * 128 * 2;
    unsigned short* wto = (unsigned short*)w; w += 2 * 32 * 128 * 2;
    float*    gp      = (float*)w;    w += 64 * 32 * 4;
    float*    m1      = (float*)w;    w += 64 * 64 * 4;
    float*    m2      = (float*)w;    w += 64 * 16 * 4;

    const int NB = (N + TPB - 1) / TPB;
    const int CS = (E + NCHK - 1) / NCHK;
    const int GB = (N + 127) / 128;   // MFMA GEMM grid (BM=128)
    const int SB = (N + 127) / 128;   // node-blocks per slice (128 nodes each)

    // ---- CSR build + weight prep ----
    hipMemsetAsync(qctr, 0, 6 * 8 * 4, stream);
    k_hist<<<NCHK, 256, 0, stream>>>(dstp, histT, E, CS);
    k_prepw<<<544, 128, 0, stream>>>(W1, W2, W3, W4, Wo, wt1, wt2, wt3, wt4, wto);
    k_scanS<<<1, 256, 0, stream>>>(histT, stg);
    k_bucket<<<NCHK, 256, 0, stream>>>(src, dstp, stg, staging, E, CS);
    k_deg<<<NBKT, 256, 0, stream>>>(staging, stg, cnt, E, N);
    k_scanA<<<NB, TPB, 0, stream>>>(cnt, rowptr, bsum, N);
    k_scanB<<<1, 512, 0, stream>>>(bsum, bscan, NB);
    k_scanC<<<NB, TPB, 0, stream>>>(rowptr, bscan, cnt, dinv, N);
    k_fill2<<<NBKT, 256, 0, stream>>>(staging, stg, rowptr, csr, E, N);

    unsigned short* agg = buf1;
    unsigned short* xs  = buf2;

    // Layer 1 (aggregate-first on 64-dim, 4 slices)
    k_castx<<<(N * 8 + 255) / 256, 256, 0, stream>>>(x, dinv, xs, N);
    k_gather_x<64, false, false, true><<<4 * SB, 256, 0, stream>>>(
        xs, rowptr, csr, dinv, nullptr, agg, qctr + 0 * 8, N, SB);
    k_gemm_mfma<64, 128, 1><<<GB, 256, 0, stream>>>(agg, wt1, nullptr, b1, buf2, N);

    // Layers 2-4 (8 slices)
    k_gemm_mfma<128, 128, 0><<<GB, 256, 0, stream>>>(buf2, wt2, dinv, nullptr, hsb, N);
    k_gather_x<128, true, true, true><<<8 * SB, 256, 0, stream>>>(
        hsb, rowptr, csr, dinv, b2, buf1, qctr + 1 * 8, N, SB);
    k_gemm_mfma<128, 128, 0><<<GB, 256, 0, stream>>>(buf1, wt3, dinv, nullptr, hsb, N);
    k_gather_x<128, true, true, true><<<8 * SB, 256, 0, stream>>>(
        hsb, rowptr, csr, dinv, b3, buf2, qctr + 2 * 8, N, SB);
    k_gemm_mfma<128, 128, 0><<<GB, 256, 0, stream>>>(buf2, wt4, dinv, nullptr, hsb, N);
    k_gather_x<128, true, true, true><<<8 * SB, 256, 0, stream>>>(
        hsb, rowptr, csr, dinv, b4, buf1, qctr + 3 * 8, N, SB);

    // Layer 5: 128 -> 32 (2 slices; fp32 out for pool)
    k_gemm_mfma<128, 32, 0><<<GB, 256, 0, stream>>>(buf1, wto, dinv, nullptr, hsb, N);
    float* hout = (float*)buf2;
    k_gather_x<32, false, true, false><<<2 * SB, 256, 0, stream>>>(
        hsb, rowptr, csr, dinv, bo, hout, qctr + 4 * 8, N, SB);

    // Mean pool + MLP head
    k_pool<<<G, 256, 0, stream>>>(hout, batch, gp, N);
    k_mlp<32, 64, true><<<(G * 64 + 255) / 256, 256, 0, stream>>>(gp, M1w, M1b, m1, G);
    k_mlp<64, 16, true><<<(G * 16 + 255) / 256, 256, 0, stream>>>(m1, M2w, M2b, m2, G);
    k_mlp<16, 8, false><<<(G * 8 + 255) / 256, 256, 0, stream>>>(m2, M3w, M3b, (float*)d_out, G);
}

// Round 10
// 628.830 us; speedup vs baseline: 2.0496x; 1.3311x over previous
//
#include <hip/hip_runtime.h>

// ---------------------------------------------------------------------------
// GCN: bucketed CSR-by-dst build + 5 x (MFMA GEMM / gather) + pool + MLP.
// Row-major bf16 tables, 16-lanes/node gather (r6 structure — both sliced
// variants measured slower: r8 row-waste, r9 issue-bound).
// Gather floor: each XCD streams the 25.6MB table once = ~189MB compulsory
// miss traffic at ~3.5TB/s miss path ~= 55-61us per D=128 gather.
// k_bucket: tile-wise LDS write-combining (4B random stores cost a 64B line
// each otherwise — the k_fill lesson from r2-r4).
// Weights split hi+lo bf16 (2x MFMA, coherent err ~4e-6); accum fp32.
// ---------------------------------------------------------------------------

static constexpr int TPB = 256;
static constexpr int NBKT = 128;   // dst buckets: bucket = dst >> 10
static constexpr int NCHK = 256;   // edge chunks
static constexpr int TILE = 2048;  // edges per bucket-scatter tile

using f32x4  = __attribute__((ext_vector_type(4))) float;
using bf16x8 = __attribute__((ext_vector_type(8))) short;

__device__ __forceinline__ float u2f(unsigned u) { return __uint_as_float(u); }

__device__ __forceinline__ unsigned short bf1(float a) {
    unsigned u = __float_as_uint(a);
    u += 0x7FFFu + ((u >> 16) & 1u);
    return (unsigned short)(u >> 16);
}

__device__ __forceinline__ unsigned bf2(float a, float b) {
    unsigned ua = __float_as_uint(a);
    unsigned ub = __float_as_uint(b);
    ua += 0x7FFFu + ((ua >> 16) & 1u);
    ub += 0x7FFFu + ((ub >> 16) & 1u);
    return (ua >> 16) | (ub & 0xFFFF0000u);
}

// ------------------------------- CSR build ---------------------------------
__global__ __launch_bounds__(256) void k_hist(const int* __restrict__ dst,
                                              int* __restrict__ histT, int E, int CS) {
    __shared__ int h[NBKT];
    int c = blockIdx.x, t = threadIdx.x;
    if (t < NBKT) h[t] = 0;
    __syncthreads();
    int e0 = c * CS, e1 = min(e0 + CS, E);
    for (int e = e0 + t; e < e1; e += 256)
        atomicAdd(&h[dst[e] >> 10], 1);
    __syncthreads();
    if (t < NBKT) histT[t * NCHK + c] = h[t];
}

__global__ __launch_bounds__(256) void k_scanS(const int* __restrict__ histT,
                                               int* __restrict__ stg) {
    constexpr int TOT = NBKT * NCHK;
    constexpr int PER = TOT / 256;
    __shared__ int s[256];
    int t = threadIdx.x;
    int base = t * PER;
    int sum = 0;
    for (int i = 0; i < PER; ++i) sum += histT[base + i];
    s[t] = sum;
    __syncthreads();
    for (int off = 1; off < 256; off <<= 1) {
        int add = (t >= off) ? s[t - off] : 0;
        __syncthreads();
        s[t] += add;
        __syncthreads();
    }
    int run = (t > 0) ? s[t - 1] : 0;
    for (int i = 0; i < PER; ++i) {
        stg[base + i] = run;
        run += histT[base + i];
    }
}

// bucket-scatter with LDS write-combining: per 2048-edge tile,
// count -> scan -> bucket-major LDS stage -> coalesced global runs.
__global__ __launch_bounds__(256) void k_bucket(const int* __restrict__ src,
                                                const int* __restrict__ dst,
                                                const int* __restrict__ stg,
                                                unsigned* __restrict__ staging,
                                                int E, int CS) {
    __shared__ int gcur[NBKT];
    __shared__ int cnt_[NBKT];
    __shared__ int base[NBKT];
    __shared__ unsigned sval[TILE];
    __shared__ unsigned char sbkt[TILE];
    int c = blockIdx.x, t = threadIdx.x;
    if (t < NBKT) gcur[t] = stg[t * NCHK + c];
    int e0 = c * CS, e1 = min(e0 + CS, E);

    for (int tb = e0; tb < e1; tb += TILE) {
        int m = min(TILE, e1 - tb);
        __syncthreads();                 // protect gcur/cnt_ from prev iter
        if (t < NBKT) cnt_[t] = 0;
        __syncthreads();
        // phase 1: load + per-bucket local offset (static 8 slots)
        int  b_[8]; unsigned v_[8]; int o_[8]; bool ok_[8];
#pragma unroll
        for (int k = 0; k < 8; ++k) {
            int e = tb + t + k * 256;
            ok_[k] = (e < tb + m);
            b_[k] = 0; v_[k] = 0; o_[k] = 0;
            if (ok_[k]) {
                int d = dst[e];
                b_[k] = d >> 10;
                v_[k] = ((unsigned)src[e] << 10) | (unsigned)(d & 1023);
                o_[k] = atomicAdd(&cnt_[b_[k]], 1);
            }
        }
        __syncthreads();
        // phase 2: exclusive scan of cnt_ (Hillis-Steele over 128)
        if (t < NBKT) base[t] = cnt_[t];
        __syncthreads();
        for (int off = 1; off < NBKT; off <<= 1) {
            int v = (t < NBKT && t >= off) ? base[t - off] : 0;
            __syncthreads();
            if (t < NBKT) base[t] += v;
            __syncthreads();
        }
        if (t < NBKT) base[t] -= cnt_[t];   // inclusive -> exclusive
        __syncthreads();
        // phase 3: scatter into bucket-major LDS
#pragma unroll
        for (int k = 0; k < 8; ++k) {
            if (ok_[k]) {
                int p = base[b_[k]] + o_[k];
                sval[p] = v_[k];
                sbkt[p] = (unsigned char)b_[k];
            }
        }
        __syncthreads();
        // phase 4: coalesced run-wise writes to global
        for (int i = t; i < m; i += 256) {
            int b = sbkt[i];
            staging[gcur[b] + (i - base[b])] = sval[i];
        }
        __syncthreads();
        if (t < NBKT) gcur[t] += cnt_[t];
    }
}

__global__ __launch_bounds__(256) void k_deg(const unsigned* __restrict__ staging,
                                             const int* __restrict__ stg,
                                             int* __restrict__ cnt, int E, int n) {
    __shared__ int deg[1024];
    int r = blockIdx.x, t = threadIdx.x;
    for (int i = t; i < 1024; i += 256) deg[i] = 0;
    __syncthreads();
    int s0 = stg[r * NCHK];
    int s1 = (r == NBKT - 1) ? E : stg[(r + 1) * NCHK];
    for (int e = s0 + t; e < s1; e += 256)
        atomicAdd(&deg[staging[e] & 1023u], 1);
    __syncthreads();
    int b = r << 10;
    for (int i = t; i < 1024; i += 256)
        if (b + i < n) cnt[b + i] = deg[i];
}

__global__ void k_scanA(const int* __restrict__ cnt, int* __restrict__ rowptr,
                        int* __restrict__ bsum, int n) {
    __shared__ int s[TPB];
    int t = threadIdx.x;
    int i = blockIdx.x * TPB + t;
    s[t] = (i < n) ? cnt[i] : 0;
    __syncthreads();
    for (int off = 1; off < TPB; off <<= 1) {
        int add = (t >= off) ? s[t - off] : 0;
        __syncthreads();
        s[t] += add;
        __syncthreads();
    }
    if (i < n) rowptr[i + 1] = s[t];
    if (t == TPB - 1) bsum[blockIdx.x] = s[t];
}

__global__ void k_scanB(const int* __restrict__ bsum, int* __restrict__ bscan, int nb) {
    __shared__ int s[512];
    int t = threadIdx.x;
    s[t] = (t < nb) ? bsum[t] : 0;
    __syncthreads();
    for (int off = 1; off < 512; off <<= 1) {
        int add = (t >= off) ? s[t - off] : 0;
        __syncthreads();
        s[t] += add;
        __syncthreads();
    }
    if (t < nb) bscan[t] = (t > 0) ? s[t - 1] : 0;
}

__global__ void k_scanC(int* __restrict__ rowptr, const int* __restrict__ bscan,
                        const int* __restrict__ cnt, float* __restrict__ dinv, int n) {
    int i = blockIdx.x * blockDim.x + threadIdx.x;
    if (i >= n) return;
    rowptr[i + 1] += bscan[i >> 8];
    dinv[i] = rsqrtf((float)cnt[i] + 1.0f);
    if (i == 0) rowptr[0] = 0;
}

__global__ __launch_bounds__(256) void k_fill2(const unsigned* __restrict__ staging,
                                               const int* __restrict__ stg,
                                               const int* __restrict__ rowptr,
                                               int* __restrict__ csr, int E, int n) {
    __shared__ int cur[1024];
    int r = blockIdx.x, t = threadIdx.x;
    int b = r << 10;
    for (int i = t; i < 1024; i += 256)
        cur[i] = (b + i < n) ? rowptr[b + i] : 0;
    __syncthreads();
    int s0 = stg[r * NCHK];
    int s1 = (r == NBKT - 1) ? E : stg[(r + 1) * NCHK];
    for (int e = s0 + t; e < s1; e += 256) {
        unsigned sd = staging[e];
        int p = atomicAdd(&cur[sd & 1023u], 1);
        csr[p] = (int)(sd >> 10);
    }
}

// xs[i,k] = bf16(x[i,k] * dinv[i]); 8 elems/thread
__global__ void k_castx(const float* __restrict__ x, const float* __restrict__ dinv,
                        unsigned short* __restrict__ xs, int n) {
    int gid = blockIdx.x * blockDim.x + threadIdx.x;
    if (gid >= n * 8) return;
    int row = gid >> 3;
    float d = dinv[row];
    const float4* xp = (const float4*)x + (size_t)gid * 2;
    float4 a = xp[0], b = xp[1];
    uint4 o;
    o.x = bf2(a.x * d, a.y * d);
    o.y = bf2(a.z * d, a.w * d);
    o.z = bf2(b.x * d, b.y * d);
    o.w = bf2(b.z * d, b.w * d);
    ((uint4*)xs)[gid] = o;
}

// ---------------------- weight prep: W -> W^T hi/lo bf16 -------------------
__global__ void k_prepw(const float* __restrict__ W1, const float* __restrict__ W2,
                        const float* __restrict__ W3, const float* __restrict__ W4,
                        const float* __restrict__ Wo,
                        unsigned short* __restrict__ wt1, unsigned short* __restrict__ wt2,
                        unsigned short* __restrict__ wt3, unsigned short* __restrict__ wt4,
                        unsigned short* __restrict__ wto) {
    int b = blockIdx.x, k = threadIdx.x;
    const float* W; unsigned short* wt; int K, OUT, nn;
    if (b < 128)      { W = W1; wt = wt1; K = 64;  OUT = 128; nn = b; }
    else if (b < 256) { W = W2; wt = wt2; K = 128; OUT = 128; nn = b - 128; }
    else if (b < 384) { W = W3; wt = wt3; K = 128; OUT = 128; nn = b - 256; }
    else if (b < 512) { W = W4; wt = wt4; K = 128; OUT = 128; nn = b - 384; }
    else              { W = Wo; wt = wto; K = 128; OUT = 32;  nn = b - 512; }
    if (nn >= OUT || k >= K) return;
    float v = W[(size_t)k * OUT + nn];
    unsigned short hi = bf1(v);
    float fhi = u2f((unsigned)hi << 16);
    unsigned short lo = bf1(v - fhi);
    wt[nn * K + k] = hi;
    wt[OUT * K + nn * K + k] = lo;
}

// ---------------------------- MFMA GEMM ------------------------------------
template <int K, int OUT, int EPI>
__global__ __launch_bounds__(256) void k_gemm_mfma(
    const unsigned short* __restrict__ Ain,
    const unsigned short* __restrict__ WT,
    const float* __restrict__ dinv,
    const float* __restrict__ bias,
    unsigned short* __restrict__ out, int n) {
    constexpr int NT = OUT / 16;   // n-tiles
    constexpr int KT = K / 32;     // k-tiles
    constexpr int CH = K / 8;      // 16B chunks per WT row
    __shared__ __align__(16) unsigned short Wl[2 * OUT * K];

    int t = threadIdx.x;
    {
        const uint4* wg = (const uint4*)WT;
        uint4* wl = (uint4*)Wl;
        for (int i = t; i < 2 * OUT * CH; i += 256) {
            int m = i / (OUT * CH);
            int r = i - m * (OUT * CH);
            int nn = r / CH, g = r - nn * CH;
            wl[m * OUT * CH + nn * CH + (g ^ (nn & 7))] = wg[i];
        }
    }

    int wid = t >> 6, lane = t & 63;
    int lr = lane & 15, lg = lane >> 4;
    int mbase = blockIdx.x * 128 + wid * 32;

    bf16x8 a[2][KT];
#pragma unroll
    for (int mt = 0; mt < 2; ++mt) {
        int row = mbase + mt * 16 + lr;
        row = row < n ? row : n - 1;
        const bf16x8* ap = (const bf16x8*)(Ain + (size_t)row * K);
#pragma unroll
        for (int kt = 0; kt < KT; ++kt)
            a[mt][kt] = ap[kt * 4 + lg];
    }

    __syncthreads();

    f32x4 acc[2][NT] = {};
#pragma unroll
    for (int nt = 0; nt < NT; ++nt) {
        int nn = nt * 16 + lr;
        int swz = nn & 7;
        int rowoff = nn * K;
#pragma unroll
        for (int kt = 0; kt < KT; ++kt) {
            int g = kt * 4 + lg;
            int off = rowoff + ((g ^ swz) * 8);
            bf16x8 bhi = *(const bf16x8*)&Wl[off];
            bf16x8 blo = *(const bf16x8*)&Wl[OUT * K + off];
#pragma unroll
            for (int mt = 0; mt < 2; ++mt) {
                acc[mt][nt] = __builtin_amdgcn_mfma_f32_16x16x32_bf16(
                    a[mt][kt], bhi, acc[mt][nt], 0, 0, 0);
                acc[mt][nt] = __builtin_amdgcn_mfma_f32_16x16x32_bf16(
                    a[mt][kt], blo, acc[mt][nt], 0, 0, 0);
            }
        }
    }

#pragma unroll
    for (int mt = 0; mt < 2; ++mt) {
        int rbase = mbase + mt * 16 + lg * 4;
        float dv[4];
        if (EPI == 0) {
#pragma unroll
            for (int r = 0; r < 4; ++r)
                dv[r] = (rbase + r < n) ? dinv[rbase + r] : 0.f;
        }
#pragma unroll
        for (int nt = 0; nt < NT; ++nt) {
            int col = nt * 16 + lr;
            float bb = (EPI == 1) ? bias[col] : 0.f;
#pragma unroll
            for (int r = 0; r < 4; ++r) {
                int row = rbase + r;
                if (row < n) {
                    float v = acc[mt][nt][r];
                    if (EPI == 0) v *= dv[r];
                    else v = fmaxf(v + bb, 0.f);
                    out[(size_t)row * OUT + col] = bf1(v);
                }
            }
        }
    }
}

// --------------------------- gather (bf16 table) ---------------------------
__device__ __forceinline__ void addbf(float* acc, uint4 w) {
    acc[0] += u2f(w.x << 16); acc[1] += u2f(w.x & 0xFFFF0000u);
    acc[2] += u2f(w.y << 16); acc[3] += u2f(w.y & 0xFFFF0000u);
    acc[4] += u2f(w.z << 16); acc[5] += u2f(w.z & 0xFFFF0000u);
    acc[6] += u2f(w.w << 16); acc[7] += u2f(w.w & 0xFFFF0000u);
}

// out_i = [relu]( dinv_i * (hs_i + sum_j hs_j) [+ bias] );  bf16 or fp32 out
template <int D, bool RELU, bool HASBIAS, bool OUTBF>
__global__ __launch_bounds__(256) void k_gather_bf(const unsigned short* __restrict__ hsb,
                                                   const int* __restrict__ rowptr,
                                                   const int* __restrict__ csr,
                                                   const float* __restrict__ dinv,
                                                   const float* __restrict__ bias,
                                                   void* __restrict__ outp, int n) {
    constexpr int TPN = D / 8;  // threads per node, 8 bf16 (16B) each
    int gid = blockIdx.x * blockDim.x + threadIdx.x;
    int node = gid / TPN;
    if (node >= n) return;
    int c = gid % TPN;
    const uint4* hb = (const uint4*)hsb;

    float acc[8];
    {
        uint4 v = hb[(size_t)node * TPN + c];
        acc[0] = u2f(v.x << 16); acc[1] = u2f(v.x & 0xFFFF0000u);
        acc[2] = u2f(v.y << 16); acc[3] = u2f(v.y & 0xFFFF0000u);
        acc[4] = u2f(v.z << 16); acc[5] = u2f(v.z & 0xFFFF0000u);
        acc[6] = u2f(v.w << 16); acc[7] = u2f(v.w & 0xFFFF0000u);
    }
    int j0 = rowptr[node], j1 = rowptr[node + 1];
    int j = j0;
    for (; j + 3 < j1; j += 4) {
        int s0 = csr[j], s1 = csr[j + 1], s2 = csr[j + 2], s3 = csr[j + 3];
        uint4 w0 = hb[(size_t)s0 * TPN + c];
        uint4 w1 = hb[(size_t)s1 * TPN + c];
        uint4 w2 = hb[(size_t)s2 * TPN + c];
        uint4 w3 = hb[(size_t)s3 * TPN + c];
        addbf(acc, w0); addbf(acc, w1); addbf(acc, w2); addbf(acc, w3);
    }
    for (; j < j1; ++j) {
        uint4 w0 = hb[(size_t)csr[j] * TPN + c];
        addbf(acc, w0);
    }

    float di = dinv[node];
    float r[8];
    if (HASBIAS) {
        float4 b0 = *(const float4*)&bias[c * 8];
        float4 b1 = *(const float4*)&bias[c * 8 + 4];
        r[0] = di * acc[0] + b0.x; r[1] = di * acc[1] + b0.y;
        r[2] = di * acc[2] + b0.z; r[3] = di * acc[3] + b0.w;
        r[4] = di * acc[4] + b1.x; r[5] = di * acc[5] + b1.y;
        r[6] = di * acc[6] + b1.z; r[7] = di * acc[7] + b1.w;
    } else {
#pragma unroll
        for (int i = 0; i < 8; ++i) r[i] = di * acc[i];
    }
    if (RELU) {
#pragma unroll
        for (int i = 0; i < 8; ++i) r[i] = fmaxf(r[i], 0.f);
    }
    if (OUTBF) {
        uint4 o;
        o.x = bf2(r[0], r[1]); o.y = bf2(r[2], r[3]);
        o.z = bf2(r[4], r[5]); o.w = bf2(r[6], r[7]);
        ((uint4*)outp)[(size_t)node * TPN + c] = o;
    } else {
        float4 o0 = {r[0], r[1], r[2], r[3]};
        float4 o1 = {r[4], r[5], r[6], r[7]};
        float4* op = (float4*)outp + (size_t)node * TPN * 2 + c * 2;
        op[0] = o0;
        op[1] = o1;
    }
}

// ------------------------------ pool + MLP ---------------------------------
__global__ __launch_bounds__(256) void k_pool(const float* __restrict__ h,
                                              const int* __restrict__ batch,
                                              float* __restrict__ g, int n) {
    __shared__ int se[2];
    __shared__ float red[8][32];
    int gi = blockIdx.x;
    int t = threadIdx.x;
    if (t == 0) {
        int lo = 0, hi = n;
        while (lo < hi) { int m = (lo + hi) >> 1; if (batch[m] < gi) lo = m + 1; else hi = m; }
        se[0] = lo;
        lo = 0; hi = n;
        while (lo < hi) { int m = (lo + hi) >> 1; if (batch[m] < gi + 1) lo = m + 1; else hi = m; }
        se[1] = lo;
    }
    __syncthreads();
    int start = se[0], end = se[1];
    int col = t & 31, sub = t >> 5;
    float acc = 0.f;
    for (int i = start + sub; i < end; i += 8)
        acc += h[(size_t)i * 32 + col];
    red[sub][col] = acc;
    __syncthreads();
    if (t < 32) {
        float s = 0.f;
#pragma unroll
        for (int q = 0; q < 8; ++q) s += red[q][t];
        float c = (float)(end - start);
        g[gi * 32 + t] = s / fmaxf(c, 1.0f);
    }
}

template <int K, int O, bool RELU>
__global__ void k_mlp(const float* __restrict__ in, const float* __restrict__ W,
                      const float* __restrict__ b, float* __restrict__ out, int G) {
    int gid = blockIdx.x * blockDim.x + threadIdx.x;
    if (gid >= G * O) return;
    int g = gid / O, j = gid % O;
    float s = b[j];
    for (int k = 0; k < K; ++k) s += in[g * K + k] * W[k * O + j];
    if (RELU) s = fmaxf(s, 0.f);
    out[gid] = s;
}

// ------------------------------- launch ------------------------------------
extern "C" void kernel_launch(void* const* d_in, const int* in_sizes, int n_in,
                              void* d_out, int out_size, void* d_ws, size_t ws_size,
                              hipStream_t stream) {
    const float* x    = (const float*)d_in[0];
    const int*   ei   = (const int*)d_in[1];
    const int*   batch= (const int*)d_in[2];
    const float* W1 = (const float*)d_in[3];  const float* b1 = (const float*)d_in[4];
    const float* W2 = (const float*)d_in[5];  const float* b2 = (const float*)d_in[6];
    const float* W3 = (const float*)d_in[7];  const float* b3 = (const float*)d_in[8];
    const float* W4 = (const float*)d_in[9];  const float* b4 = (const float*)d_in[10];
    const float* Wo = (const float*)d_in[11]; const float* bo = (const float*)d_in[12];
    const float* M1w = (const float*)d_in[13]; const float* M1b = (const float*)d_in[14];
    const float* M2w = (const float*)d_in[15]; const float* M2b = (const float*)d_in[16];
    const float* M3w = (const float*)d_in[17]; const float* M3b = (const float*)d_in[18];

    const int N = in_sizes[0] / 64;   // 100000
    const int E = in_sizes[1] / 2;    // 1600000
    const int G = out_size / 8;       // 64
    const int* src  = ei;
    const int* dstp = ei + E;

    // workspace
    char* w = (char*)d_ws;
    unsigned short* buf1 = (unsigned short*)w; w += (size_t)N * 128 * 2;
    unsigned short* buf2 = (unsigned short*)w; w += (size_t)N * 128 * 4;  // also fp32 hout
    unsigned short* hsb  = (unsigned short*)w; w += (size_t)N * 128 * 2;
    int*      csr     = (int*)w;      w += (size_t)E * 4;
    unsigned* staging = (unsigned*)w; w += (size_t)E * 4;
    int*      histT   = (int*)w;      w += NBKT * NCHK * 4;
    int*      stg     = (int*)w;      w += NBKT * NCHK * 4;
    int*      cnt     = (int*)w;      w += (size_t)N * 4;
    int*      rowptr  = (int*)w;      w += (size_t)(N + 4) * 4;
    int*      bsum    = (int*)w;      w += 4096;
    int*      bscan   = (int*)w;      w += 4096;
    float*    dinv    = (float*)w;    w += (size_t)N * 4;
    unsigned short* wt1 = (unsigned short*)w; w += 2 * 128 * 64 * 2;
    unsigned short* wt2 = (unsigned short*)w; w += 2 * 128 * 128 * 2;
    unsigned short* wt3 = (unsigned short*)w; w += 2 * 128 * 128 * 2;
    unsigned short* wt4 = (unsigned short*)w; w += 2 * 128 * 128 * 2;
    unsigned short* wto = (unsigned short*)w; w += 2 * 32 * 128 * 2;
    float*    gp      = (float*)w;    w += 64 * 32 * 4;
    float*    m1      = (float*)w;    w += 64 * 64 * 4;
    float*    m2      = (float*)w;    w += 64 * 16 * 4;

    const int NB = (N + TPB - 1) / TPB;
    const int CS = (E + NCHK - 1) / NCHK;
    const int GB = (N + 127) / 128;   // MFMA GEMM grid (BM=128)

    // ---- CSR build + weight prep ----
    k_hist<<<NCHK, 256, 0, stream>>>(dstp, histT, E, CS);
    k_prepw<<<544, 128, 0, stream>>>(W1, W2, W3, W4, Wo, wt1, wt2, wt3, wt4, wto);
    k_scanS<<<1, 256, 0, stream>>>(histT, stg);
    k_bucket<<<NCHK, 256, 0, stream>>>(src, dstp, stg, staging, E, CS);
    k_deg<<<NBKT, 256, 0, stream>>>(staging, stg, cnt, E, N);
    k_scanA<<<NB, TPB, 0, stream>>>(cnt, rowptr, bsum, N);
    k_scanB<<<1, 512, 0, stream>>>(bsum, bscan, NB);
    k_scanC<<<NB, TPB, 0, stream>>>(rowptr, bscan, cnt, dinv, N);
    k_fill2<<<NBKT, 256, 0, stream>>>(staging, stg, rowptr, csr, E, N);

    unsigned short* agg = buf1;
    unsigned short* xs  = buf2;

    // Layer 1 (aggregate-first on 64-dim)
    k_castx<<<(N * 8 + 255) / 256, 256, 0, stream>>>(x, dinv, xs, N);
    k_gather_bf<64, false, false, true><<<(N * 8 + 255) / 256, 256, 0, stream>>>(
        xs, rowptr, csr, dinv, nullptr, agg, N);
    k_gemm_mfma<64, 128, 1><<<GB, 256, 0, stream>>>(agg, wt1, nullptr, b1, buf2, N);

    // Layers 2-4
    k_gemm_mfma<128, 128, 0><<<GB, 256, 0, stream>>>(buf2, wt2, dinv, nullptr, hsb, N);
    k_gather_bf<128, true, true, true><<<(N * 16 + 255) / 256, 256, 0, stream>>>(
        hsb, rowptr, csr, dinv, b2, buf1, N);
    k_gemm_mfma<128, 128, 0><<<GB, 256, 0, stream>>>(buf1, wt3, dinv, nullptr, hsb, N);
    k_gather_bf<128, true, true, true><<<(N * 16 + 255) / 256, 256, 0, stream>>>(
        hsb, rowptr, csr, dinv, b3, buf2, N);
    k_gemm_mfma<128, 128, 0><<<GB, 256, 0, stream>>>(buf2, wt4, dinv, nullptr, hsb, N);
    k_gather_bf<128, true, true, true><<<(N * 16 + 255) / 256, 256, 0, stream>>>(
        hsb, rowptr, csr, dinv, b4, buf1, N);

    // Layer 5: 128 -> 32 (fp32 out for pool)
    k_gemm_mfma<128, 32, 0><<<GB, 256, 0, stream>>>(buf1, wto, dinv, nullptr, hsb, N);
    float* hout = (float*)buf2;
    k_gather_bf<32, false, true, false><<<(N * 4 + 255) / 256, 256, 0, stream>>>(
        hsb, rowptr, csr, dinv, bo, hout, N);

    // Mean pool + MLP head
    k_pool<<<G, 256, 0, stream>>>(hout, batch, gp, N);
    k_mlp<32, 64, true><<<(G * 64 + 255) / 256, 256, 0, stream>>>(gp, M1w, M1b, m1, G);
    k_mlp<64, 16, true><<<(G * 16 + 255) / 256, 256, 0, stream>>>(m1, M2w, M2b, m2, G);
    k_mlp<16, 8, false><<<(G * 8 + 255) / 256, 256, 0, stream>>>(m2, M3w, M3b, (float*)d_out, G);
}